// Round 5
// baseline (41.273 us; speedup 1.0000x reference)
//
#include <hip/hip_runtime.h>

#define GRIDD  76                 // grid dim (H = W)
#define NROWS  255                // anchors(3) * attrs(85)
#define GG     (GRIDD * GRIDD)    // 5776
#define UROWS  128                // rem rows per unit (half 1 overlaps rem=127)
#define UPITCH 76                 // dwords, ZERO pad: linear slab, conflict-free both phases
#define UDW    (UROWS * UPITCH)   // 9728 dwords = 38912 B per buffer
#define NUNITS 2432               // 16 b * 76 h * 2 halves
#define NBLK   512                // persistent blocks, 2/CU

typedef __attribute__((address_space(3))) unsigned lds_u32;
typedef __attribute__((address_space(1))) unsigned glb_u32;

__device__ __forceinline__ void gll16(const float* g, float* l) {
    // async global->LDS, 16B/lane; LDS dest = wave-uniform base + lane*16
    __builtin_amdgcn_global_load_lds((const glb_u32*)g, (lds_u32*)l, 16, 0, 0);
}

__device__ __forceinline__ void stage_unit(const float* __restrict__ x,
                                           unsigned u, float* buf,
                                           unsigned wid, unsigned lane)
{
    const unsigned b    = u / 152u;
    const unsigned hr   = u - b * 152u;
    const unsigned h    = hr >> 1;
    const unsigned half = hr & 1u;
    const float* src = x + (size_t)b * (NROWS * GG)
                         + (size_t)(half * 127u) * GG + (size_t)h * GRIDD;
    #pragma unroll
    for (unsigned k = 0; k < 5u; ++k) {
        unsigned i = k * 512u + (wid << 6) + lane;      // float4 index 0..2431
        if (i < 2432u) {                                // k=4: waves 0-5 only (uniform)
            unsigned row = i / 19u;
            unsigned c4  = (i - row * 19u) << 2;
            gll16(src + (size_t)row * GG + c4,
                  buf + (size_t)((wid << 6) + k * 512u) * 4u);  // + lane*16B implicit
        }
    }
}

__global__ __launch_bounds__(512, 4) void yolo_head_kernel(
    const float* __restrict__ x, const int* __restrict__ dimp,
    float* __restrict__ out)
{
    __shared__ float buf[2][UDW];     // 77824 B -> 2 blocks/CU
    // XCD-chunked bijective swizzle (512 = 8*64): a block's contiguous unit
    // range (and its rem-seam neighbors) stays on one XCD L2.
    const unsigned lb   = (blockIdx.x & 7u) * 64u + (blockIdx.x >> 3);
    const unsigned t    = threadIdx.x;
    const unsigned wid  = t >> 6;
    const unsigned lane = t & 63u;
    const float stride  = (float)(*dimp / GRIDD);       // 608/76 = 8
    const float mB      = -0.1f * stride;

    // contiguous unit range: 2432/512 = 19/4 units per block (4 or 5)
    const unsigned u0 = (lb * 19u) >> 2;
    const unsigned u1 = ((lb + 1u) * 19u) >> 2;

    stage_unit(x, u0, buf[0], wid, lane);
    __syncthreads();                  // drains vmcnt -> buf[0] ready

    unsigned p = 0;
    for (unsigned u = u0; u < u1; ++u) {
        if (u + 1u < u1)              // prefetch next unit under this unit's compute
            stage_unit(x, u + 1u, buf[p ^ 1u], wid, lane);

        // ---- phase 2: transform + transposed store from buf[p] ----
        const unsigned b    = u / 152u;
        const unsigned hr   = u - b * 152u;
        const unsigned h    = hr >> 1;
        const unsigned rbase = (hr & 1u) * 127u;
        const float fh = (float)h;
        float* __restrict__ outbh = out + (size_t)(b * GRIDD + h) * (GRIDD * NROWS);
        const float* bc = buf[p];

        #pragma unroll
        for (unsigned j = 0; j < 5u; ++j) {
            unsigned tt = wid + (j << 3);               // 38 tiles / 8 waves
            if (tt < 38u) {                             // j=4: waves 0-5 (uniform)
                const unsigned rc  = tt & 1u;
                const unsigned wc  = tt >> 1;           // w quad-column 0..18
                const unsigned r   = (rc << 6) + lane;  // slab row 0..127
                const unsigned rem = rbase + r;         // 0..254
                const unsigned a    = (rem >= 170u) ? 2u : ((rem >= 85u) ? 1u : 0u);
                const unsigned attr = rem - a * 85u;
                const bool  wh  = (attr == 2u) | (attr == 3u);
                const bool  isx = (attr == 0u);
                float anc = 0.f;
                if (attr == 2u) anc = (a == 0u) ? 12.f : ((a == 1u) ? 19.f : 40.f);
                if (attr == 3u) anc = (a == 0u) ? 16.f : ((a == 1u) ? 36.f : 28.f);
                const float sgn = wh ? 1.f : -1.f;
                const float A   = (attr < 2u) ? 1.2f * stride : 1.f;
                const float B0  = (attr == 1u) ? (fh * stride + mB) : 0.f;

                // lane stride 19 quads, 19 mod 8 = 3 -> conflict-free b128
                const float4 vv = *reinterpret_cast<const float4*>(&bc[r * UPITCH + (wc << 2)]);
                float* __restrict__ dst = outbh + rem;
                #pragma unroll
                for (unsigned i = 0; i < 4u; ++i) {
                    const float v = (i == 0) ? vv.x : (i == 1) ? vv.y : (i == 2) ? vv.z : vv.w;
                    const float w = (float)((wc << 2) + i);
                    const float e = __expf(sgn * v);
                    const float sig = __builtin_amdgcn_rcpf(1.0f + e);
                    const float Bi  = isx ? fmaf(w, stride, mB) : B0;
                    const float o   = wh ? e * anc : fmaf(sig, A, Bi);
                    dst[(size_t)((wc << 2) + i) * NROWS] = o;   // 256B contiguous run
                }
            }
        }
        __syncthreads();              // buf[p] reads done + next unit's gll drained
        p ^= 1u;
    }
}

extern "C" void kernel_launch(void* const* d_in, const int* in_sizes, int n_in,
                              void* d_out, int out_size, void* d_ws, size_t ws_size,
                              hipStream_t stream) {
    const float* x  = (const float*)d_in[0];
    const int* dimp = (const int*)d_in[1];
    float* out      = (float*)d_out;
    yolo_head_kernel<<<NBLK, 512, 0, stream>>>(x, dimp, out);
}

// Round 6
// 33.101 us; speedup vs baseline: 1.2469x; 1.2469x over previous
//
#include <hip/hip_runtime.h>

#define GRIDD  76                 // grid dim (H = W)
#define NROWS  255                // anchors(3) * attrs(85)
#define GG     (GRIDD * GRIDD)    // 5776
#define UROWS  128                // rem rows per block (half 1 overlaps rem=127)
#define UPITCH 76                 // dwords, ZERO pad: linear slab; gll16 dest linear,
                                  // phase-2 lane stride 19 quads (3 mod 8) -> conflict-free
#define UDW    (UROWS * UPITCH)   // 9728 dwords = 38912 B -> 4 blocks/CU

typedef __attribute__((address_space(3))) unsigned lds_u32;
typedef __attribute__((address_space(1))) unsigned glb_u32;

__device__ __forceinline__ void gll16(const float* g, float* l) {
    // async global->LDS, 16B/lane; LDS dest = wave-uniform base + lane*16
    __builtin_amdgcn_global_load_lds((const glb_u32*)g, (lds_u32*)l, 16, 0, 0);
}

__global__ __launch_bounds__(512, 8) void yolo_head_kernel(
    const float* __restrict__ x, const int* __restrict__ dimp,
    float* __restrict__ out)
{
    __shared__ float buf[UDW];
    // Round-4 XCD-bijective swizzle (2432 = 8*304): both halves of a column and
    // neighboring h share an XCD L2 -> seam cache-lines merge (WRITE 92.4MB proven).
    const unsigned lb   = (blockIdx.x & 7u) * 304u + (blockIdx.x >> 3);
    const unsigned b    = lb / (GRIDD * 2);
    const unsigned hr   = lb - b * (GRIDD * 2);
    const unsigned h    = hr >> 1;
    const unsigned rbase = (hr & 1u) * 127u;           // staged rem rows rbase..rbase+127
    const unsigned t    = threadIdx.x;
    const unsigned wid  = t >> 6;
    const unsigned lane = t & 63u;
    const float stride  = (float)(*dimp / GRIDD);      // 608/76 = 8
    const float mB      = -0.1f * stride;

    // ---- phase 1: async-stage [128 rem][76 w] slab, linear LDS dest ----
    const float* __restrict__ src = x + (size_t)b * (NROWS * GG)
                                      + (size_t)rbase * GG + (size_t)h * GRIDD;
    #pragma unroll
    for (unsigned k = 0; k < 5u; ++k) {
        unsigned i = k * 512u + (wid << 6) + lane;     // float4 chunk 0..2431
        if (i < 2432u) {                               // k=4: waves 0-5 full (uniform)
            unsigned row = i / 19u;
            unsigned c4  = (i - row * 19u) << 2;
            gll16(src + (size_t)row * GG + c4,
                  buf + (size_t)(k * 512u + (wid << 6)) * 4u);  // +lane*16B implicit
        }
    }
    __syncthreads();                                   // drains vmcnt -> slab ready

    // ---- phase 2: wave tiles of 64 rem x 4 w; lane = rem ----
    const float fh = (float)h;
    float* __restrict__ outbh = out + (size_t)(b * GRIDD + h) * (GRIDD * NROWS);

    #pragma unroll
    for (unsigned j = 0; j < 5u; ++j) {
        unsigned tt = wid + (j << 3);                  // 38 tiles / 8 waves
        if (tt < 38u) {                                // j=4: waves 0-5 (uniform)
            const unsigned rc  = tt & 1u;
            const unsigned wc  = tt >> 1;              // w quad-column 0..18
            const unsigned r   = (rc << 6) + lane;     // slab row 0..127
            const unsigned rem = rbase + r;            // 0..254
            const unsigned a    = (rem >= 170u) ? 2u : ((rem >= 85u) ? 1u : 0u);
            const unsigned attr = rem - a * 85u;
            const bool  wh  = (attr == 2u) | (attr == 3u);
            const bool  isx = (attr == 0u);
            float anc = 0.f;
            if (attr == 2u) anc = (a == 0u) ? 12.f : ((a == 1u) ? 19.f : 40.f);
            if (attr == 3u) anc = (a == 0u) ? 16.f : ((a == 1u) ? 36.f : 28.f);
            const float sgn = wh ? 1.f : -1.f;
            const float A   = (attr < 2u) ? 1.2f * stride : 1.f;
            const float B0  = (attr == 1u) ? (fh * stride + mB) : 0.f;

            const float4 vv = *reinterpret_cast<const float4*>(&buf[r * UPITCH + (wc << 2)]);
            float* __restrict__ dst = outbh + rem;
            #pragma unroll
            for (unsigned i = 0; i < 4u; ++i) {
                const float v = (i == 0) ? vv.x : (i == 1) ? vv.y : (i == 2) ? vv.z : vv.w;
                const float w = (float)((wc << 2) + i);
                const float e = __expf(sgn * v);
                const float sig = __builtin_amdgcn_rcpf(1.0f + e);
                const float Bi  = isx ? fmaf(w, stride, mB) : B0;
                const float o   = wh ? e * anc : fmaf(sig, A, Bi);
                dst[(size_t)((wc << 2) + i) * NROWS] = o;   // 256B contiguous run
            }
        }
    }
}

extern "C" void kernel_launch(void* const* d_in, const int* in_sizes, int n_in,
                              void* d_out, int out_size, void* d_ws, size_t ws_size,
                              hipStream_t stream) {
    const float* x  = (const float*)d_in[0];
    const int* dimp = (const int*)d_in[1];
    float* out      = (float*)d_out;
    const int B = in_sizes[0] / (NROWS * GG);   // 16
    yolo_head_kernel<<<B * GRIDD * 2, 512, 0, stream>>>(x, dimp, out);
}